// Round 1
// baseline (2992.633 us; speedup 1.0000x reference)
//
#include <hip/hip_runtime.h>
#include <math.h>

// Problem constants (fixed by setup_inputs)
#define B_ 16
#define S_ 1024
#define D_ 512
#define H_ 4
#define MROWS (B_ * S_)          // 16384
#define INV_TEMP 0.044194173824159216f  // 1/sqrt(512)

// Tile config: 64x64 C-tile, K-chunk 16, 256 threads, 4x4 micro-tile/thread
#define BM 64
#define BN 64
#define BK 16

// ---------------------------------------------------------------------------
// Kernel A: v = ELU(x @ W_h^T + b_h)
//   x: [MROWS, D] row-major; W: [D(out e), D(in d)] row-major (so C = A·B^T)
// ---------------------------------------------------------------------------
__global__ __launch_bounds__(256)
void gemm_v(const float* __restrict__ x, const float* __restrict__ W,
            const float* __restrict__ bias, float* __restrict__ v)
{
    __shared__ float As[BK][BM + 1];
    __shared__ float Bs[BK][BN + 1];
    const int bm = blockIdx.y * BM;   // row block in [0,16384)
    const int bn = blockIdx.x * BN;   // col block in [0,512)
    const int t  = threadIdx.x;
    const int tx = t & 15, ty = t >> 4;
    const int lrow = t >> 2;          // 0..63
    const int lk4  = (t & 3) * 4;     // 0,4,8,12

    float acc[4][4] = {};
    for (int k0 = 0; k0 < D_; k0 += BK) {
        const float4 a4 = *(const float4*)(x + (size_t)(bm + lrow) * D_ + k0 + lk4);
        As[lk4 + 0][lrow] = a4.x; As[lk4 + 1][lrow] = a4.y;
        As[lk4 + 2][lrow] = a4.z; As[lk4 + 3][lrow] = a4.w;
        const float4 b4 = *(const float4*)(W + (size_t)(bn + lrow) * D_ + k0 + lk4);
        Bs[lk4 + 0][lrow] = b4.x; Bs[lk4 + 1][lrow] = b4.y;
        Bs[lk4 + 2][lrow] = b4.z; Bs[lk4 + 3][lrow] = b4.w;
        __syncthreads();
#pragma unroll
        for (int kk = 0; kk < BK; ++kk) {
            float a[4], b[4];
#pragma unroll
            for (int i = 0; i < 4; ++i) a[i] = As[kk][ty * 4 + i];
#pragma unroll
            for (int j = 0; j < 4; ++j) b[j] = Bs[kk][tx * 4 + j];
#pragma unroll
            for (int i = 0; i < 4; ++i)
#pragma unroll
                for (int j = 0; j < 4; ++j) acc[i][j] = fmaf(a[i], b[j], acc[i][j]);
        }
        __syncthreads();
    }
#pragma unroll
    for (int i = 0; i < 4; ++i) {
        const int row = bm + ty * 4 + i;
#pragma unroll
        for (int j = 0; j < 4; ++j) {
            const int col = bn + tx * 4 + j;
            float z = acc[i][j] + bias[col];
            z = (z > 0.0f) ? z : (expf(z) - 1.0f);   // ELU, alpha=1
            v[(size_t)row * D_ + col] = z;
        }
    }
}

// ---------------------------------------------------------------------------
// Kernel B: scores[b,q,k] = (x_b[q]·x_b[k]) * INV_TEMP * mask(b,q,k)
//   mask = (k > q) || (event_type[b,k] == 0)      [keeps FUTURE + PAD keys]
// ---------------------------------------------------------------------------
__global__ __launch_bounds__(256)
void gemm_scores(const float* __restrict__ x, const int* __restrict__ etype,
                 float* __restrict__ scores)
{
    __shared__ float As[BK][BM + 1];
    __shared__ float Bs[BK][BN + 1];
    const int b  = blockIdx.z;
    const float* xb = x + (size_t)b * S_ * D_;
    const int bq = blockIdx.y * BM;
    const int bk = blockIdx.x * BN;
    const int t  = threadIdx.x;
    const int tx = t & 15, ty = t >> 4;
    const int lrow = t >> 2;
    const int lk4  = (t & 3) * 4;

    float acc[4][4] = {};
    for (int k0 = 0; k0 < D_; k0 += BK) {
        const float4 a4 = *(const float4*)(xb + (size_t)(bq + lrow) * D_ + k0 + lk4);
        As[lk4 + 0][lrow] = a4.x; As[lk4 + 1][lrow] = a4.y;
        As[lk4 + 2][lrow] = a4.z; As[lk4 + 3][lrow] = a4.w;
        const float4 b4 = *(const float4*)(xb + (size_t)(bk + lrow) * D_ + k0 + lk4);
        Bs[lk4 + 0][lrow] = b4.x; Bs[lk4 + 1][lrow] = b4.y;
        Bs[lk4 + 2][lrow] = b4.z; Bs[lk4 + 3][lrow] = b4.w;
        __syncthreads();
#pragma unroll
        for (int kk = 0; kk < BK; ++kk) {
            float a[4], bb[4];
#pragma unroll
            for (int i = 0; i < 4; ++i) a[i] = As[kk][ty * 4 + i];
#pragma unroll
            for (int j = 0; j < 4; ++j) bb[j] = Bs[kk][tx * 4 + j];
#pragma unroll
            for (int i = 0; i < 4; ++i)
#pragma unroll
                for (int j = 0; j < 4; ++j) acc[i][j] = fmaf(a[i], bb[j], acc[i][j]);
        }
        __syncthreads();
    }
#pragma unroll
    for (int i = 0; i < 4; ++i) {
        const int q = bq + ty * 4 + i;
#pragma unroll
        for (int j = 0; j < 4; ++j) {
            const int k = bk + tx * 4 + j;
            const bool m = (k > q) || (etype[b * S_ + k] == 0);
            scores[((size_t)b * S_ + q) * S_ + k] = m ? acc[i][j] * INV_TEMP : 0.0f;
        }
    }
}

// ---------------------------------------------------------------------------
// Kernel R: inv[row] = 1 / max(sqrt(sum_k scores[row,k]^2), 1e-5)
// ---------------------------------------------------------------------------
__global__ __launch_bounds__(256)
void rownorm(const float* __restrict__ scores, float* __restrict__ inv)
{
    const int row = blockIdx.x;   // 0..16383
    const float4 v4 = ((const float4*)(scores + (size_t)row * S_))[threadIdx.x];
    float ss = v4.x * v4.x + v4.y * v4.y + v4.z * v4.z + v4.w * v4.w;
#pragma unroll
    for (int off = 32; off > 0; off >>= 1) ss += __shfl_down(ss, off, 64);
    __shared__ float red[4];
    if ((threadIdx.x & 63) == 0) red[threadIdx.x >> 6] = ss;
    __syncthreads();
    if (threadIdx.x == 0) {
        const float tot = red[0] + red[1] + red[2] + red[3];
        inv[row] = 1.0f / fmaxf(sqrtf(tot), 1e-5f);
    }
}

// ---------------------------------------------------------------------------
// Kernel C: xnew[b,q,e] = inv[b,q] * sum_k scores[b,q,k] * v[b,k,e]
//           xbuf = xnew ; out = accum ? out + xnew : xnew
// ---------------------------------------------------------------------------
__global__ __launch_bounds__(256)
void gemm_out(const float* __restrict__ scores, const float* __restrict__ v,
              const float* __restrict__ inv, float* __restrict__ xout,
              float* __restrict__ out, const int accum)
{
    __shared__ float As[BK][BM + 1];
    __shared__ float Bs[BK][BN];        // row-major [k][e], float4-written
    const int b  = blockIdx.z;
    const float* A  = scores + (size_t)b * S_ * S_;
    const float* Bv = v + (size_t)b * S_ * D_;
    const int bq = blockIdx.y * BM;     // 16 blocks
    const int be = blockIdx.x * BN;     // 8 blocks
    const int t  = threadIdx.x;
    const int tx = t & 15, ty = t >> 4;
    const int lrow = t >> 2;            // A-loader
    const int lk4  = (t & 3) * 4;
    const int brow = t >> 4;            // B-loader: 0..15
    const int bcol4 = (t & 15) * 4;

    float acc[4][4] = {};
    for (int k0 = 0; k0 < S_; k0 += BK) {
        const float4 a4 = *(const float4*)(A + (size_t)(bq + lrow) * S_ + k0 + lk4);
        As[lk4 + 0][lrow] = a4.x; As[lk4 + 1][lrow] = a4.y;
        As[lk4 + 2][lrow] = a4.z; As[lk4 + 3][lrow] = a4.w;
        *(float4*)&Bs[brow][bcol4] =
            *(const float4*)(Bv + (size_t)(k0 + brow) * D_ + be + bcol4);
        __syncthreads();
#pragma unroll
        for (int kk = 0; kk < BK; ++kk) {
            float a[4], bb[4];
#pragma unroll
            for (int i = 0; i < 4; ++i) a[i] = As[kk][ty * 4 + i];
#pragma unroll
            for (int j = 0; j < 4; ++j) bb[j] = Bs[kk][tx * 4 + j];
#pragma unroll
            for (int i = 0; i < 4; ++i)
#pragma unroll
                for (int j = 0; j < 4; ++j) acc[i][j] = fmaf(a[i], bb[j], acc[i][j]);
        }
        __syncthreads();
    }
#pragma unroll
    for (int i = 0; i < 4; ++i) {
        const int q = bq + ty * 4 + i;
        const float s = inv[b * S_ + q];
#pragma unroll
        for (int j = 0; j < 4; ++j) {
            const int e = be + tx * 4 + j;
            const float val = acc[i][j] * s;
            const size_t o = ((size_t)b * S_ + q) * D_ + e;
            xout[o] = val;
            out[o]  = accum ? (out[o] + val) : val;
        }
    }
}

// ---------------------------------------------------------------------------
// Host launcher. Workspace layout (needs ~128.1 MiB):
//   xbuf   [MROWS*D]  fp32   33,554,432 B  @ 0
//   vbuf   [MROWS*D]  fp32   33,554,432 B  @ 33,554,432
//   sbuf   [B*S*S]    fp32   67,108,864 B  @ 67,108,864
//   ibuf   [MROWS]    fp32       65,536 B  @ 134,217,728
// ---------------------------------------------------------------------------
extern "C" void kernel_launch(void* const* d_in, const int* in_sizes, int n_in,
                              void* d_out, int out_size, void* d_ws, size_t ws_size,
                              hipStream_t stream) {
    const float* x0    = (const float*)d_in[0];          // [B,S,D]
    const int*   etype = (const int*)d_in[2];            // [B,S]
    const float* W     = (const float*)d_in[3];          // [H,D,D]
    const float* bias  = (const float*)d_in[4];          // [H,D]
    float* out = (float*)d_out;

    char* ws = (char*)d_ws;
    float* xbuf = (float*)(ws);
    float* vbuf = (float*)(ws + 33554432);
    float* sbuf = (float*)(ws + 67108864);
    float* ibuf = (float*)(ws + 134217728);

    const dim3 gridA(D_ / BN, MROWS / BM);       // (8, 256)
    const dim3 gridB(S_ / BN, S_ / BM, B_);      // (16, 16, 16)
    const dim3 gridR(MROWS);                     // 16384
    const dim3 gridC(D_ / BN, S_ / BM, B_);      // (8, 16, 16)

    for (int h = 0; h < H_; ++h) {
        const float* xcur = (h == 0) ? x0 : xbuf;
        const float* Wh = W + (size_t)h * D_ * D_;
        const float* bh = bias + (size_t)h * D_;
        gemm_v     <<<gridA, 256, 0, stream>>>(xcur, Wh, bh, vbuf);
        gemm_scores<<<gridB, 256, 0, stream>>>(xcur, etype, sbuf);
        rownorm    <<<gridR, 256, 0, stream>>>(sbuf, ibuf);
        gemm_out   <<<gridC, 256, 0, stream>>>(sbuf, vbuf, ibuf, xbuf, out, h > 0);
    }
}

// Round 2
// 490.126 us; speedup vs baseline: 6.1058x; 6.1058x over previous
//
#include <hip/hip_runtime.h>
#include <math.h>

#define B_ 16
#define S_ 1024
#define D_ 512
#define H_ 4
#define INV_TEMP 0.044194173824159216f   // 1/sqrt(512)
#define C_SCALE 0.00390625f              // 2^-8: keeps head-4 scores inside fp16 range
#define OUT_SCALE 256.0f

typedef _Float16 f16;
typedef _Float16 f16x8 __attribute__((ext_vector_type(8)));
typedef _Float16 f16x4 __attribute__((ext_vector_type(4)));
typedef float f32x4 __attribute__((ext_vector_type(4)));

#define AS1(p) ((const __attribute__((address_space(1))) void*)(p))
#define AS3(p) ((__attribute__((address_space(3))) void*)(p))

// ---------------------------------------------------------------------------
// Stage a 128x32 f16 tile (row-major, row stride `ld` elements) into LDS.
// LDS layout: flat [128][32] f16. Thread t covers (row=t>>2, 8-elem chunk=t&3)
// and (row+64, same chunk) -> matches wave-uniform-base + lane*16 semantics.
// ---------------------------------------------------------------------------
__device__ __forceinline__ void stage128x32(const f16* __restrict__ src, int ld,
                                            char* lds0, int t)
{
    const f16* g0 = src + (size_t)(t >> 2) * ld + (t & 3) * 8;
    __builtin_amdgcn_global_load_lds(AS1(g0), AS3(lds0 + t * 16), 16, 0, 0);
    const f16* g1 = g0 + (size_t)64 * ld;
    __builtin_amdgcn_global_load_lds(AS1(g1), AS3(lds0 + 4096 + t * 16), 16, 0, 0);
}

// 16 MFMAs on the staged chunk: wave tile 64x64 = 4x4 tiles of 16x16.
// A-frag: A[m=lane&15][k=quad*8+j]; B-frag: B[n=lane&15][k=quad*8+j].
__device__ __forceinline__ void mma_chunk(const char* ldsA, const char* ldsB,
                                          int wm, int wn, int lr, int quad,
                                          f32x4 (*acc)[4])
{
    f16x8 af[4], bf[4];
#pragma unroll
    for (int i = 0; i < 4; ++i)
        af[i] = *(const f16x8*)(ldsA + ((wm * 64 + i * 16 + lr) * 32 + quad * 8) * 2);
#pragma unroll
    for (int j = 0; j < 4; ++j)
        bf[j] = *(const f16x8*)(ldsB + ((wn * 64 + j * 16 + lr) * 32 + quad * 8) * 2);
#pragma unroll
    for (int i = 0; i < 4; ++i)
#pragma unroll
        for (int j = 0; j < 4; ++j)
            acc[i][j] = __builtin_amdgcn_mfma_f32_16x16x32_f16(af[i], bf[j], acc[i][j], 0, 0, 0);
}

// Full K-loop: A is [128 x K] at `A` (row-major ld ldA), B is [128 x K] (B^T form).
__device__ __forceinline__ void gemm_core(const f16* A, int ldA, const f16* Bm, int ldB,
                                          int K, char* lds, int t, int wm, int wn,
                                          int lr, int quad, f32x4 (*acc)[4])
{
    for (int k0 = 0; k0 < K; k0 += 32) {
        stage128x32(A + k0, ldA, lds, t);
        stage128x32(Bm + k0, ldB, lds + 8192, t);
        __syncthreads();
        mma_chunk(lds, lds + 8192, wm, wn, lr, quad, acc);
        __syncthreads();
    }
}

// ---------------------------------------------------------------------------
// fp32 -> fp16 convert (vectorized), exact-size grids only
// ---------------------------------------------------------------------------
__global__ __launch_bounds__(256)
void k_conv(const float* __restrict__ src, f16* __restrict__ dst)
{
    const int i = blockIdx.x * 256 + threadIdx.x;
    const float4 v = ((const float4*)src)[i];
    f16x4 h; h[0] = (f16)v.x; h[1] = (f16)v.y; h[2] = (f16)v.z; h[3] = (f16)v.w;
    ((f16x4*)dst)[i] = h;
}

// ---------------------------------------------------------------------------
// v^T = ELU(x @ W_h^T + b_h)^T  stored as [B][D][S] fp16
// M-dim = flattened rows s (16384), N-dim = e (512)
// ---------------------------------------------------------------------------
__global__ __launch_bounds__(256)
void k_gemm_v(const f16* __restrict__ xh, const f16* __restrict__ Wh,
              const float* __restrict__ bias, f16* __restrict__ vT)
{
    __shared__ __align__(16) char lds[16384];
    const int t = threadIdx.x;
    const int w = t >> 6, lane = t & 63, lr = lane & 15, quad = lane >> 4;
    const int wm = w & 1, wn = w >> 1;
    const int bm = blockIdx.x * 128;   // s rows
    const int bn = blockIdx.y * 128;   // e cols
    f32x4 acc[4][4] = {};
    gemm_core(xh + (size_t)bm * D_, D_, Wh + (size_t)bn * D_, D_, D_,
              lds, t, wm, wn, lr, quad, acc);
#pragma unroll
    for (int j = 0; j < 4; ++j) {
        const int e = bn + wn * 64 + j * 16 + lr;
        const float be = bias[e];
#pragma unroll
        for (int i = 0; i < 4; ++i) {
            const int m = bm + wm * 64 + i * 16 + quad * 4;
            const int batch = m >> 10, s = m & 1023;
            f16x4 hv;
#pragma unroll
            for (int r = 0; r < 4; ++r) {
                float z = acc[i][j][r] + be;
                z = (z > 0.0f) ? z : (expf(z) - 1.0f);
                hv[r] = (f16)z;
            }
            *(f16x4*)(vT + ((size_t)batch * D_ + e) * S_ + s) = hv;
        }
    }
}

// ---------------------------------------------------------------------------
// scores[b][q][k] = mask ? (x_q . x_k) * INV_TEMP * C_SCALE : 0   (fp16)
// Uses symmetry of x.x^T: M-dim = keys k, N-dim = queries q -> contiguous stores.
// ---------------------------------------------------------------------------
__global__ __launch_bounds__(256)
void k_scores(const f16* __restrict__ xh, const int* __restrict__ etype,
              f16* __restrict__ sh)
{
    __shared__ __align__(16) char lds[16384];
    const int t = threadIdx.x;
    const int w = t >> 6, lane = t & 63, lr = lane & 15, quad = lane >> 4;
    const int wm = w & 1, wn = w >> 1;
    const int b = blockIdx.z;
    const int bk = blockIdx.x * 128;   // keys  (m-dim)
    const int bq = blockIdx.y * 128;   // query (n-dim)
    const f16* xb = xh + (size_t)b * S_ * D_;
    f32x4 acc[4][4] = {};
    gemm_core(xb + (size_t)bk * D_, D_, xb + (size_t)bq * D_, D_, D_,
              lds, t, wm, wn, lr, quad, acc);
    const float sc = INV_TEMP * C_SCALE;
#pragma unroll
    for (int i = 0; i < 4; ++i) {
        const int k4 = bk + wm * 64 + i * 16 + quad * 4;
        const int4 et = *(const int4*)(etype + b * S_ + k4);
        const int ev[4] = {et.x, et.y, et.z, et.w};
#pragma unroll
        for (int j = 0; j < 4; ++j) {
            const int q = bq + wn * 64 + j * 16 + lr;
            f16x4 hv;
#pragma unroll
            for (int r = 0; r < 4; ++r) {
                const bool keep = ((k4 + r) > q) || (ev[r] == 0);
                hv[r] = (f16)(keep ? acc[i][j][r] * sc : 0.0f);
            }
            *(f16x4*)(sh + ((size_t)b * S_ + q) * S_ + k4) = hv;
        }
    }
}

// ---------------------------------------------------------------------------
// inv[row] = 1 / (C_SCALE * max(norm_true, 1e-5)), norm from fp16 scores
// one wave per row
// ---------------------------------------------------------------------------
__global__ __launch_bounds__(256)
void k_rownorm(const f16* __restrict__ sh, float* __restrict__ inv)
{
    const int w = threadIdx.x >> 6, lane = threadIdx.x & 63;
    const int row = blockIdx.x * 4 + w;
    const f16* p = sh + (size_t)row * S_;
    const f16x8 a = *(const f16x8*)(p + lane * 8);
    const f16x8 c = *(const f16x8*)(p + 512 + lane * 8);
    float ss = 0.0f;
#pragma unroll
    for (int r = 0; r < 8; ++r) {
        const float x = (float)a[r]; ss += x * x;
        const float y = (float)c[r]; ss += y * y;
    }
#pragma unroll
    for (int off = 32; off; off >>= 1) ss += __shfl_down(ss, off, 64);
    if (lane == 0) {
        const float norm_true = sqrtf(ss) * OUT_SCALE;   // undo C_SCALE
        inv[row] = 1.0f / (C_SCALE * fmaxf(norm_true, 1e-5f));
    }
}

// ---------------------------------------------------------------------------
// x_new[b][q][e] = inv[b][q] * sum_k scores[b][q][k] * v[b][k][e]
// M-dim = e (from vT), N-dim = q (from scores rows) -> contiguous f32x4 stores.
// out = accum ? out + x_new : x_new ; xh = fp16(x_new)
// ---------------------------------------------------------------------------
__global__ __launch_bounds__(256)
void k_out(const f16* __restrict__ vT, const f16* __restrict__ sh,
           const float* __restrict__ inv, f16* __restrict__ xh,
           float* __restrict__ out, const int accum)
{
    __shared__ __align__(16) char lds[16384];
    const int t = threadIdx.x;
    const int w = t >> 6, lane = t & 63, lr = lane & 15, quad = lane >> 4;
    const int wm = w & 1, wn = w >> 1;
    const int b = blockIdx.z;
    const int be = blockIdx.x * 128;   // e (m-dim)
    const int bq = blockIdx.y * 128;   // q (n-dim)
    f32x4 acc[4][4] = {};
    gemm_core(vT + ((size_t)b * D_ + be) * S_, S_,
              sh + ((size_t)b * S_ + bq) * S_, S_, S_,
              lds, t, wm, wn, lr, quad, acc);
#pragma unroll
    for (int j = 0; j < 4; ++j) {
        const int q = bq + wn * 64 + j * 16 + lr;
        const float scl = inv[b * S_ + q];
#pragma unroll
        for (int i = 0; i < 4; ++i) {
            const int e4 = be + wm * 64 + i * 16 + quad * 4;
            const size_t o = ((size_t)b * S_ + q) * D_ + e4;
            f32x4 xnew;
            f16x4 hx;
#pragma unroll
            for (int r = 0; r < 4; ++r) {
                xnew[r] = acc[i][j][r] * scl;
                hx[r] = (f16)xnew[r];
            }
            f32x4 val = xnew;
            if (accum) { const f32x4 old = *(const f32x4*)(out + o); val = val + old; }
            *(f32x4*)(out + o) = val;
            *(f16x4*)(xh + o) = hx;
        }
    }
}

// ---------------------------------------------------------------------------
// Workspace layout (bytes):
//   xh  fp16 [B][S][D]   @ 0        (16 MiB)
//   vT  fp16 [B][D][S]   @ 16 MiB   (16 MiB)
//   sh  fp16 [B][S][S]   @ 32 MiB   (32 MiB)
//   Wh  fp16 [H][D][D]   @ 64 MiB   ( 2 MiB)
//   inv fp32 [B*S]       @ 66 MiB   (64 KiB)
// ---------------------------------------------------------------------------
extern "C" void kernel_launch(void* const* d_in, const int* in_sizes, int n_in,
                              void* d_out, int out_size, void* d_ws, size_t ws_size,
                              hipStream_t stream) {
    const float* x0    = (const float*)d_in[0];
    const int*   etype = (const int*)d_in[2];
    const float* W     = (const float*)d_in[3];
    const float* bias  = (const float*)d_in[4];
    float* out = (float*)d_out;

    char* ws = (char*)d_ws;
    f16*   xh  = (f16*)(ws);
    f16*   vT  = (f16*)(ws + (16u << 20));
    f16*   sh  = (f16*)(ws + (32u << 20));
    f16*   Wh  = (f16*)(ws + (64u << 20));
    float* inv = (float*)(ws + (66u << 20));

    // one-time converts
    k_conv<<<8192, 256, 0, stream>>>(x0, xh);   // 16*1024*512 / 4 / 256
    k_conv<<<1024, 256, 0, stream>>>(W, Wh);    // 4*512*512   / 4 / 256

    const dim3 gridV(128, 4);        // 16384/128 x 512/128
    const dim3 gridS(8, 8, B_);      // 1024/128 x 1024/128 x B
    const dim3 gridR(4096);          // 16384 rows / 4 per block
    const dim3 gridO(4, 8, B_);      // 512/128 x 1024/128 x B

    for (int h = 0; h < H_; ++h) {
        k_gemm_v <<<gridV, 256, 0, stream>>>(xh, Wh + (size_t)h * D_ * D_,
                                             bias + (size_t)h * D_, vT);
        k_scores <<<gridS, 256, 0, stream>>>(xh, etype, sh);
        k_rownorm<<<gridR, 256, 0, stream>>>(sh, inv);
        k_out    <<<gridO, 256, 0, stream>>>(vT, sh, inv, xh, out, h > 0);
    }
}